// Round 10
// baseline (134.160 us; speedup 1.0000x reference)
//
#include <hip/hip_runtime.h>
#include <math.h>

#define PI_F      3.14159265358979323846f
#define TWO_PI_F  6.28318530717958647692f
#define INV_2PI_F 0.15915494309189533577f

// ---- raw-instruction math helpers ----
__device__ __forceinline__ float fsqrt(float x)  { return __builtin_amdgcn_sqrtf(x); }
__device__ __forceinline__ float frcp(float x)   { return __builtin_amdgcn_rcpf(x); }
__device__ __forceinline__ float frsq(float x)   { return __builtin_amdgcn_rsqf(x); }
__device__ __forceinline__ float fexp2(float x)  { return __builtin_amdgcn_exp2f(x); }
__device__ __forceinline__ float flog2(float x)  { return __builtin_amdgcn_logf(x); }
__device__ __forceinline__ float fsin(float x)   { return __builtin_amdgcn_sinf(x * INV_2PI_F); }
__device__ __forceinline__ float fcos(float x)   { return __builtin_amdgcn_cosf(x * INV_2PI_F); }

// ============================================================================
// MATH — VERBATIM from the R9 passing kernel. A razor-edge pixel in the fixed
// dataset flips its |h_diff|>pi branch under sub-ulp perturbation (R3/R7/R8
// all failed with identical absmax 0.2109375). DO NOT change expression trees,
// constants, or scalar/vector form anywhere in ciede2000_px or its callees.
// ============================================================================

__device__ __forceinline__ float fast_atan2(float y, float x) {
    float ax = fabsf(x), ay = fabsf(y);
    float mx = fmaxf(ax, ay), mn = fminf(ax, ay);
    float r = mn * frcp(mx);
    float s = r * r;
    float p = __fmaf_rn(s, -0.01172120f, 0.05265332f);
    p = __fmaf_rn(s, p, -0.11643287f);
    p = __fmaf_rn(s, p,  0.19354346f);
    p = __fmaf_rn(s, p, -0.33262347f);
    p = __fmaf_rn(s, p,  0.99997726f);
    float th = r * p;
    th = (ay > ax)   ? (1.57079632679f - th) : th;
    th = (x < 0.0f)  ? (PI_F - th)           : th;
    th = (y < 0.0f)  ? -th                   : th;
    th = (mx == 0.0f) ? 0.0f : th;            // atan2(0,0) = 0
    return th;
}

__device__ __forceinline__ float srgb_lin(float c) {
    float u = __fmaf_rn(c, 1.0f / 1.055f, 0.055f / 1.055f);
    float p = fexp2(2.4f * flog2(u));
    float l = c * (1.0f / 12.92f);
    return (c > 0.04045f) ? p : l;
}

__device__ __forceinline__ float labf(float t) {
    float cr = fexp2(0.333333333333f * flog2(t));
    float ln = __fmaf_rn(7.787f, t, 4.0f / 29.0f);
    return (t > 0.008856f) ? cr : ln;
}

__device__ __forceinline__ void rgb2lab(float r, float g, float b,
                                        float& L, float& A, float& B) {
    r = srgb_lin(r); g = srgb_lin(g); b = srgb_lin(b);
    float xn = 0.4339463f * r + 0.3762135f * g + 0.1898252f * b;
    float yn = 0.212671f  * r + 0.71516f   * g + 0.072169f  * b;
    float zn = 0.0177566f * r + 0.1094694f * g + 0.8727056f * b;
    float fx = labf(xn);
    float fy = labf(yn);
    float fz = labf(zn);
    L = __fmaf_rn(116.0f, fy, -16.0f);
    A = 500.0f * (fx - fy);
    B = 200.0f * (fy - fz);
}

__device__ __forceinline__ float ciede2000_px(float r1, float g1, float bl1,
                                              float r2, float g2, float bl2) {
    float L1, A1, B1, L2, A2, B2;
    rgb2lab(r1, g1, bl1, L1, A1, B1);
    rgb2lab(r2, g2, bl2, L2, A2, B2);

    const float P25_7 = 6103515625.0f;  // 25^7

    float C1 = fsqrt(__fmaf_rn(A1, A1, B1 * B1));
    float C2 = fsqrt(__fmaf_rn(A2, A2, B2 * B2));
    float Cbar = 0.5f * (C1 + C2);
    float cb2 = Cbar * Cbar;
    float c7 = cb2 * cb2 * cb2 * Cbar;
    float G = __fmaf_rn(-0.5f * c7, frsq(__fmaf_rn(c7, c7, __fmaf_rn(P25_7, c7, 1e-20f))), 0.5f);
    float s = 1.0f + G;
    float a1p = A1 * s, a2p = A2 * s;
    float C1p = fsqrt(__fmaf_rn(a1p, a1p, B1 * B1));
    float C2p = fsqrt(__fmaf_rn(a2p, a2p, B2 * B2));

    // ---- hue block: literal reference semantics (R2/R4/R9-verified). ----
    float h1 = fast_atan2(B1, a1p); h1 = (h1 < 0.0f) ? h1 + TWO_PI_F : h1;
    float h2 = fast_atan2(B2, a2p); h2 = (h2 < 0.0f) ? h2 + TWO_PI_F : h2;

    float h_diff = h2 - h1;
    float h_sum  = h1 + h2;
    float CC = C1p * C2p;
    bool cc0 = (CC == 0.0f);

    float dH = (h_diff > PI_F) ? (h_diff - TWO_PI_F)
             : ((h_diff < -PI_F) ? (h_diff + TWO_PI_F) : h_diff);
    if (cc0) dH = 0.0f;
    float dH_term = 2.0f * fsqrt(CC) * fsin(0.5f * dH);

    bool mask = (!cc0) && (fabsf(h_diff) > PI_F);
    float Hbar = h_sum;
    if (mask) Hbar = (h_sum < TWO_PI_F) ? (h_sum + TWO_PI_F) : (h_sum - TWO_PI_F);
    if (cc0)  Hbar = h_sum * 2.0f;
    Hbar *= 0.5f;
    // ---- end hue block ----

    float Lbar = 0.5f * (L1 + L2);
    float lt = Lbar - 50.0f;
    float tmp = lt * lt;
    float SL = __fmaf_rn(0.015f * tmp, frsq(20.0f + tmp), 1.0f);

    float Cbarp = 0.5f * (C1p + C2p);
    float SC = __fmaf_rn(0.045f, Cbarp, 1.0f);

    float ch = fcos(Hbar);
    float sh = fsin(Hbar);
    float c2 = __fmaf_rn(2.0f * ch, ch, -1.0f);
    float s2 = 2.0f * sh * ch;
    float c3 = ch * c2 - sh * s2;
    float s3 = sh * c2 + ch * s2;
    float c4 = __fmaf_rn(2.0f * c2, c2, -1.0f);
    float s4 = 2.0f * s2 * c2;
    float T1 = __fmaf_rn(ch, 0.86602540378f, sh * 0.5f);                 // cos(H-30deg)
    float T3 = __fmaf_rn(c3, 0.99452189536f, -s3 * 0.10452846327f);      // cos(3H+6deg)
    float T4 = __fmaf_rn(c4, 0.45399049974f, s4 * 0.89100652419f);       // cos(4H-63deg)
    float T = 1.0f - 0.17f * T1 + 0.24f * c2 + 0.32f * T3 - 0.20f * T4;
    float SH = __fmaf_rn(0.015f * Cbarp, T, 1.0f);

    float PQ  = SC * SH;
    float inv = frcp(SL * PQ);
    float L_term = (L2 - L1) * PQ * inv;
    float C_term = (C2p - C1p) * (SL * SH) * inv;
    float H_term = dH_term * (SL * SC) * inv;

    float cp2 = Cbarp * Cbarp;
    float c7p = cp2 * cp2 * cp2 * Cbarp;
    float Rc = 2.0f * c7p * frsq(__fmaf_rn(c7p, c7p, __fmaf_rn(P25_7, c7p, 1e-20f)));

    float hd = __fmaf_rn(Hbar, 2.752769787f, -13.2123465f);
    float v  = 1.04719755119f * fexp2(-(hd * hd));       // = 2*dtheta in (0, pi/3]
    float w  = v * v;
    float sp = __fmaf_rn(w, -1.0f / 5040.0f, 1.0f / 120.0f);
    sp = __fmaf_rn(w, sp, -1.0f / 6.0f);
    sp = __fmaf_rn(w, sp, 1.0f);
    float sin2dt = v * sp;
    float R_term = -sin2dt * Rc * C_term * H_term;

    float dE2 = __fmaf_rn(L_term, L_term,
                __fmaf_rn(C_term, C_term,
                __fmaf_rn(H_term, H_term, R_term)));
    return fsqrt(fmaxf(dE2, 0.0f)) * 0.01f;
}

// ============================================================================
// SHELL — persistent grid + software prefetch. 2048 blocks = exactly 8/CU,
// all co-resident; each thread does ITERS strided float2 iterations, loading
// iteration k+1's data before computing iteration k so only the first global
// load stalls (theory: R9's ~30% idle = per-block cold-load ramps from 32
// sequential short blocks per CU).
// ============================================================================

#define NBLOCKS 2048
#define NTHREADS 256
#define STRIDE (NBLOCKS * NTHREADS)       // 524288 float2 per sweep
#define ITERS 4                           // 2097152 / 524288

struct Px {
    float2 r1, g1, b1, r2, g2, b2;
};

__device__ __forceinline__ Px load_px(const float* __restrict__ img1,
                                      const float* __restrict__ img2, int idx) {
    const int PLANE2 = 131072;              // 512*512/2
    int n = idx >> 17;                      // batch index
    int j = idx & (PLANE2 - 1);             // float2 index within plane
    const float2* p1 = reinterpret_cast<const float2*>(img1) + (size_t)n * 3 * PLANE2;
    const float2* p2 = reinterpret_cast<const float2*>(img2) + (size_t)n * 3 * PLANE2;
    Px v;
    v.r1 = p1[j]; v.g1 = p1[j + PLANE2]; v.b1 = p1[j + 2 * PLANE2];
    v.r2 = p2[j]; v.g2 = p2[j + PLANE2]; v.b2 = p2[j + 2 * PLANE2];
    return v;
}

__global__ __launch_bounds__(NTHREADS) void ciede_kernel(
    const float* __restrict__ img1, const float* __restrict__ img2,
    float* __restrict__ out, int n2_total) {
    int tid = blockIdx.x * NTHREADS + threadIdx.x;
    if (tid >= n2_total) return;

    float2* out2 = reinterpret_cast<float2*>(out);

    Px cur = load_px(img1, img2, tid);
    #pragma unroll
    for (int k = 0; k < ITERS; ++k) {
        int idx  = tid + k * STRIDE;
        int nidx = idx + STRIDE;
        Px nxt;
        if (k + 1 < ITERS && nidx < n2_total) nxt = load_px(img1, img2, nidx);
        float2 o;
        o.x = ciede2000_px(cur.r1.x, cur.g1.x, cur.b1.x, cur.r2.x, cur.g2.x, cur.b2.x);
        o.y = ciede2000_px(cur.r1.y, cur.g1.y, cur.b1.y, cur.r2.y, cur.g2.y, cur.b2.y);
        if (idx < n2_total) out2[idx] = o;
        cur = nxt;
    }
}

extern "C" void kernel_launch(void* const* d_in, const int* in_sizes, int n_in,
                              void* d_out, int out_size, void* d_ws, size_t ws_size,
                              hipStream_t stream) {
    const float* img1 = (const float*)d_in[0];
    const float* img2 = (const float*)d_in[1];
    float* out = (float*)d_out;

    int n2 = out_size / 2;           // 2,097,152 float2 outputs
    ciede_kernel<<<NBLOCKS, NTHREADS, 0, stream>>>(img1, img2, out, n2);
}

// Round 11
// 130.881 us; speedup vs baseline: 1.0251x; 1.0251x over previous
//
#include <hip/hip_runtime.h>
#include <math.h>

#define PI_F      3.14159265358979323846f
#define TWO_PI_F  6.28318530717958647692f
#define INV_2PI_F 0.15915494309189533577f

// ---- raw-instruction math helpers ----
__device__ __forceinline__ float fsqrt(float x)  { return __builtin_amdgcn_sqrtf(x); }
__device__ __forceinline__ float frcp(float x)   { return __builtin_amdgcn_rcpf(x); }
__device__ __forceinline__ float frsq(float x)   { return __builtin_amdgcn_rsqf(x); }
__device__ __forceinline__ float fexp2(float x)  { return __builtin_amdgcn_exp2f(x); }
__device__ __forceinline__ float flog2(float x)  { return __builtin_amdgcn_logf(x); }
__device__ __forceinline__ float fsin(float x)   { return __builtin_amdgcn_sinf(x * INV_2PI_F); }
__device__ __forceinline__ float fcos(float x)   { return __builtin_amdgcn_cosf(x * INV_2PI_F); }

// ============================================================================
// MATH — VERBATIM from the R9 passing kernel. A razor-edge pixel in the fixed
// dataset flips its |h_diff|>pi branch under sub-ulp perturbation (R3/R7/R8
// all failed with identical absmax 0.2109375). DO NOT change expression trees,
// constants, or scalar/vector form anywhere in ciede2000_px or its callees.
// ============================================================================

__device__ __forceinline__ float fast_atan2(float y, float x) {
    float ax = fabsf(x), ay = fabsf(y);
    float mx = fmaxf(ax, ay), mn = fminf(ax, ay);
    float r = mn * frcp(mx);
    float s = r * r;
    float p = __fmaf_rn(s, -0.01172120f, 0.05265332f);
    p = __fmaf_rn(s, p, -0.11643287f);
    p = __fmaf_rn(s, p,  0.19354346f);
    p = __fmaf_rn(s, p, -0.33262347f);
    p = __fmaf_rn(s, p,  0.99997726f);
    float th = r * p;
    th = (ay > ax)   ? (1.57079632679f - th) : th;
    th = (x < 0.0f)  ? (PI_F - th)           : th;
    th = (y < 0.0f)  ? -th                   : th;
    th = (mx == 0.0f) ? 0.0f : th;            // atan2(0,0) = 0
    return th;
}

__device__ __forceinline__ float srgb_lin(float c) {
    float u = __fmaf_rn(c, 1.0f / 1.055f, 0.055f / 1.055f);
    float p = fexp2(2.4f * flog2(u));
    float l = c * (1.0f / 12.92f);
    return (c > 0.04045f) ? p : l;
}

__device__ __forceinline__ float labf(float t) {
    float cr = fexp2(0.333333333333f * flog2(t));
    float ln = __fmaf_rn(7.787f, t, 4.0f / 29.0f);
    return (t > 0.008856f) ? cr : ln;
}

__device__ __forceinline__ void rgb2lab(float r, float g, float b,
                                        float& L, float& A, float& B) {
    r = srgb_lin(r); g = srgb_lin(g); b = srgb_lin(b);
    float xn = 0.4339463f * r + 0.3762135f * g + 0.1898252f * b;
    float yn = 0.212671f  * r + 0.71516f   * g + 0.072169f  * b;
    float zn = 0.0177566f * r + 0.1094694f * g + 0.8727056f * b;
    float fx = labf(xn);
    float fy = labf(yn);
    float fz = labf(zn);
    L = __fmaf_rn(116.0f, fy, -16.0f);
    A = 500.0f * (fx - fy);
    B = 200.0f * (fy - fz);
}

__device__ __forceinline__ float ciede2000_px(float r1, float g1, float bl1,
                                              float r2, float g2, float bl2) {
    float L1, A1, B1, L2, A2, B2;
    rgb2lab(r1, g1, bl1, L1, A1, B1);
    rgb2lab(r2, g2, bl2, L2, A2, B2);

    const float P25_7 = 6103515625.0f;  // 25^7

    float C1 = fsqrt(__fmaf_rn(A1, A1, B1 * B1));
    float C2 = fsqrt(__fmaf_rn(A2, A2, B2 * B2));
    float Cbar = 0.5f * (C1 + C2);
    float cb2 = Cbar * Cbar;
    float c7 = cb2 * cb2 * cb2 * Cbar;
    float G = __fmaf_rn(-0.5f * c7, frsq(__fmaf_rn(c7, c7, __fmaf_rn(P25_7, c7, 1e-20f))), 0.5f);
    float s = 1.0f + G;
    float a1p = A1 * s, a2p = A2 * s;
    float C1p = fsqrt(__fmaf_rn(a1p, a1p, B1 * B1));
    float C2p = fsqrt(__fmaf_rn(a2p, a2p, B2 * B2));

    // ---- hue block: literal reference semantics (R2/R4/R9-verified). ----
    float h1 = fast_atan2(B1, a1p); h1 = (h1 < 0.0f) ? h1 + TWO_PI_F : h1;
    float h2 = fast_atan2(B2, a2p); h2 = (h2 < 0.0f) ? h2 + TWO_PI_F : h2;

    float h_diff = h2 - h1;
    float h_sum  = h1 + h2;
    float CC = C1p * C2p;
    bool cc0 = (CC == 0.0f);

    float dH = (h_diff > PI_F) ? (h_diff - TWO_PI_F)
             : ((h_diff < -PI_F) ? (h_diff + TWO_PI_F) : h_diff);
    if (cc0) dH = 0.0f;
    float dH_term = 2.0f * fsqrt(CC) * fsin(0.5f * dH);

    bool mask = (!cc0) && (fabsf(h_diff) > PI_F);
    float Hbar = h_sum;
    if (mask) Hbar = (h_sum < TWO_PI_F) ? (h_sum + TWO_PI_F) : (h_sum - TWO_PI_F);
    if (cc0)  Hbar = h_sum * 2.0f;
    Hbar *= 0.5f;
    // ---- end hue block ----

    float Lbar = 0.5f * (L1 + L2);
    float lt = Lbar - 50.0f;
    float tmp = lt * lt;
    float SL = __fmaf_rn(0.015f * tmp, frsq(20.0f + tmp), 1.0f);

    float Cbarp = 0.5f * (C1p + C2p);
    float SC = __fmaf_rn(0.045f, Cbarp, 1.0f);

    float ch = fcos(Hbar);
    float sh = fsin(Hbar);
    float c2 = __fmaf_rn(2.0f * ch, ch, -1.0f);
    float s2 = 2.0f * sh * ch;
    float c3 = ch * c2 - sh * s2;
    float s3 = sh * c2 + ch * s2;
    float c4 = __fmaf_rn(2.0f * c2, c2, -1.0f);
    float s4 = 2.0f * s2 * c2;
    float T1 = __fmaf_rn(ch, 0.86602540378f, sh * 0.5f);                 // cos(H-30deg)
    float T3 = __fmaf_rn(c3, 0.99452189536f, -s3 * 0.10452846327f);      // cos(3H+6deg)
    float T4 = __fmaf_rn(c4, 0.45399049974f, s4 * 0.89100652419f);       // cos(4H-63deg)
    float T = 1.0f - 0.17f * T1 + 0.24f * c2 + 0.32f * T3 - 0.20f * T4;
    float SH = __fmaf_rn(0.015f * Cbarp, T, 1.0f);

    float PQ  = SC * SH;
    float inv = frcp(SL * PQ);
    float L_term = (L2 - L1) * PQ * inv;
    float C_term = (C2p - C1p) * (SL * SH) * inv;
    float H_term = dH_term * (SL * SC) * inv;

    float cp2 = Cbarp * Cbarp;
    float c7p = cp2 * cp2 * cp2 * Cbarp;
    float Rc = 2.0f * c7p * frsq(__fmaf_rn(c7p, c7p, __fmaf_rn(P25_7, c7p, 1e-20f)));

    float hd = __fmaf_rn(Hbar, 2.752769787f, -13.2123465f);
    float v  = 1.04719755119f * fexp2(-(hd * hd));       // = 2*dtheta in (0, pi/3]
    float w  = v * v;
    float sp = __fmaf_rn(w, -1.0f / 5040.0f, 1.0f / 120.0f);
    sp = __fmaf_rn(w, sp, -1.0f / 6.0f);
    sp = __fmaf_rn(w, sp, 1.0f);
    float sin2dt = v * sp;
    float R_term = -sin2dt * Rc * C_term * H_term;

    float dE2 = __fmaf_rn(L_term, L_term,
                __fmaf_rn(C_term, C_term,
                __fmaf_rn(H_term, H_term, R_term)));
    return fsqrt(fmaxf(dE2, 0.0f)) * 0.01f;
}

// ============================================================================
// SHELL — R9 structure (2 px/thread, one float2 per plane) but with 1-WAVE
// BLOCKS (64 threads). Theory: 256-thread blocks refill CUs at 4-wave
// granularity, sagging average residency to ~4.7 waves/SIMD (Occupancy 58%)
// while each wave is a near-serial ~40-deep trans dependency chain needing
// ~8 waves to cover. Wave-granular blocks let the CU back-fill slots
// immediately. Single-variable experiment: math + per-thread work identical
// to R9.
// ============================================================================

__global__ __launch_bounds__(64) void ciede_kernel(
    const float* __restrict__ img1, const float* __restrict__ img2,
    float* __restrict__ out, int n2_total) {
    int idx = blockIdx.x * 64 + threadIdx.x;
    if (idx >= n2_total) return;

    const int PLANE2 = 131072;              // 512*512/2
    int n = idx >> 17;                      // batch index
    int j = idx & (PLANE2 - 1);             // float2 index within plane

    const float2* p1 = reinterpret_cast<const float2*>(img1) + (size_t)n * 3 * PLANE2;
    const float2* p2 = reinterpret_cast<const float2*>(img2) + (size_t)n * 3 * PLANE2;

    float2 r1 = p1[j], g1 = p1[j + PLANE2], b1 = p1[j + 2 * PLANE2];
    float2 r2 = p2[j], g2 = p2[j + PLANE2], b2 = p2[j + 2 * PLANE2];

    float2 o;
    o.x = ciede2000_px(r1.x, g1.x, b1.x, r2.x, g2.x, b2.x);
    o.y = ciede2000_px(r1.y, g1.y, b1.y, r2.y, g2.y, b2.y);
    reinterpret_cast<float2*>(out)[idx] = o;
}

extern "C" void kernel_launch(void* const* d_in, const int* in_sizes, int n_in,
                              void* d_out, int out_size, void* d_ws, size_t ws_size,
                              hipStream_t stream) {
    const float* img1 = (const float*)d_in[0];
    const float* img2 = (const float*)d_in[1];
    float* out = (float*)d_out;

    int n2 = out_size / 2;           // 2,097,152 float2 work-items
    int grid = (n2 + 63) / 64;       // 32768 one-wave blocks
    ciede_kernel<<<grid, 64, 0, stream>>>(img1, img2, out, n2);
}